// Round 5
// baseline (229.324 us; speedup 1.0000x reference)
//
#include <hip/hip_runtime.h>
#include <math.h>

#define B_ 4
#define L_ 2048
#define S_ 2048
#define H_ 8
#define E_ 64
#define BH_ (B_*H_)
#define EPS 1e-6f

typedef __attribute__((ext_vector_type(8))) short short8;
typedef __attribute__((ext_vector_type(4))) float f32x4;

__device__ __forceinline__ unsigned short f2bf(float f) {
    unsigned int u = __float_as_uint(f);
    u = (u + 0x7fffu + ((u >> 16) & 1u)) >> 16;   // RNE
    return (unsigned short)u;
}

__device__ __forceinline__ float bf2f(unsigned short u) {
    return __uint_as_float(((unsigned int)u) << 16);
}

__device__ __forceinline__ float fast_tanh(float x) {
    float e = __expf(2.0f * x);
    return 1.0f - 2.0f / (e + 1.0f);
}

// XOR-swizzled LDS byte offset: rows of 128B, 16B chunks swizzled by row&7.
__device__ __forceinline__ int swb(int row, int byteoff) {
    return row * 128 + ((((byteoff >> 4) ^ (row & 7)) << 4) | (byteoff & 15));
}

// ---------------------------------------------------------------------------
// K0 (fused preprocessing, partitioned grid):
//  blocks [0,2048):    q transform  -> qt  [B,H,L,E] bf16
//  blocks [2048,4096): k transform  -> kt  [B,H,S,E] bf16
//  blocks [4096,5120): v transpose  -> vt  [B,H,E,S] bf16
// ---------------------------------------------------------------------------
__global__ __launch_bounds__(256) void pre_kernel(
    const float* __restrict__ xq, const float* __restrict__ xk,
    const float* __restrict__ xv,
    unsigned short* __restrict__ qt, unsigned short* __restrict__ kt,
    unsigned short* __restrict__ vt,
    const float* __restrict__ dwp, const float* __restrict__ dpp)
{
    __shared__ float ls[64][65];
    int bx = blockIdx.x;
    if (bx < 4096) {
        const float* x = (bx < 2048) ? xq : xk;
        unsigned short* xt = (bx < 2048) ? qt : kt;
        int g = (bx & 2047) * 256 + threadIdx.x;   // over B*L*E = 524288
        int e = g & 63;
        int bl = g >> 6;
        int b = bl >> 11;
        int l = bl & 2047;
        size_t base = (size_t)bl * (H_ * E_) + e;
        float v[8], s = 0.f, q = 0.f;
#pragma unroll
        for (int h = 0; h < 8; ++h) {
            float t = x[base + h * E_];
            v[h] = t; s += t; q += t * t;
        }
        float mean = s * 0.125f;
        float var = (q - s * mean) * (1.f / 7.f);   // ddof=1, N=8
        var = fmaxf(var, 0.f);
        float inv = 1.f / (sqrtf(var) + EPS);
        float wsc = dwp[0] * inv;
        float d = dpp[0];
#pragma unroll
        for (int h = 0; h < 8; ++h) {
            float t = fast_tanh(v[h] * wsc) * d;
            xt[((size_t)(b * H_ + h) * L_ + l) * E_ + e] = f2bf(t);
        }
    } else {
        int t2 = bx - 4096;
        int s0 = (t2 & 31) * 64;
        int h = (t2 >> 5) & 7, b = t2 >> 8;
        int t = threadIdx.x;
#pragma unroll
        for (int i = 0; i < 4; ++i) {
            int idx = t + i * 256;
            int r = idx >> 4, c4 = (idx & 15) * 4;
            const float4 f = *(const float4*)&xv[((size_t)(b * S_ + s0 + r) * H_ + h) * E_ + c4];
            ls[r][c4] = f.x; ls[r][c4 + 1] = f.y; ls[r][c4 + 2] = f.z; ls[r][c4 + 3] = f.w;
        }
        __syncthreads();
        size_t ob = (size_t)(b * H_ + h) * E_ * S_ + s0;
#pragma unroll
        for (int i = 0; i < 16; ++i) {
            int idx = t + i * 256;
            int e = idx >> 6, s = idx & 63;
            vt[ob + (size_t)e * S_ + s] = f2bf(ls[s][e]);
        }
    }
}

// ---------------------------------------------------------------------------
// K1: partial Gram. grid 512 = 32 bh x 16 s-chunks of 128. Each block stages
// its 128x64 kt tile in LDS, transposed frag reads, 16 MFMA per wave, then
// in-block 4-wave reduce -> f32 partial G [blk][4096] + partial ksum.
// ---------------------------------------------------------------------------
__global__ __launch_bounds__(256) void gramp_kernel(
    const unsigned short* __restrict__ kt, float* __restrict__ Gp,
    float* __restrict__ ksump)
{
    __shared__ unsigned short ks[128 * 72];   // pad 72: transpose-friendly
    __shared__ float gs[4096];
    __shared__ float kss[64];
    int bh = blockIdx.x >> 4, sc = blockIdx.x & 15;
    const unsigned short* src = kt + ((size_t)bh * S_ + sc * 128) * E_;
    int tid = threadIdx.x, lane = tid & 63, w = tid >> 6;
    int m = lane & 15, quad = lane >> 4;
    // stage 128x64 bf16 tile (16KB), coalesced b128
#pragma unroll
    for (int i = 0; i < 4; ++i) {
        int u = tid + i * 256;                 // 1024 short8 units
        int s = u >> 3, e8 = u & 7;
        *(short8*)&ks[s * 72 + e8 * 8] = *(const short8*)(src + u * 8);
    }
    __syncthreads();
    // wave w handles s-chunk [w*32, w*32+32): A[m=e][k=s] frags via LDS transpose
    int s0 = w * 32;
    short8 af[4];
    float ksp[4] = {0.f, 0.f, 0.f, 0.f};
#pragma unroll
    for (int i = 0; i < 4; ++i) {
        short8 a;
#pragma unroll
        for (int kk = 0; kk < 8; ++kk) {
            unsigned short uv = ks[(s0 + quad * 8 + kk) * 72 + i * 16 + m];
            a[kk] = (short)uv;
            ksp[i] += bf2f(uv);
        }
        af[i] = a;
    }
    f32x4 acc[4][4];
#pragma unroll
    for (int i = 0; i < 4; ++i)
#pragma unroll
        for (int j = 0; j < 4; ++j) {
            acc[i][j] = (f32x4){0.f, 0.f, 0.f, 0.f};
            acc[i][j] = __builtin_amdgcn_mfma_f32_16x16x32_bf16(af[i], af[j], acc[i][j], 0, 0, 0);
        }
#pragma unroll
    for (int i = 0; i < 4; ++i) {
        ksp[i] += __shfl_xor(ksp[i], 16);
        ksp[i] += __shfl_xor(ksp[i], 32);
    }
    for (int w2 = 0; w2 < 4; ++w2) {
        if (w == w2) {
#pragma unroll
            for (int i = 0; i < 4; ++i)
#pragma unroll
                for (int j = 0; j < 4; ++j)
#pragma unroll
                    for (int r = 0; r < 4; ++r) {
                        int idx = (i * 16 + quad * 4 + r) * 64 + j * 16 + m;
                        if (w2 == 0) gs[idx] = acc[i][j][r]; else gs[idx] += acc[i][j][r];
                    }
            if (lane < 16) {
#pragma unroll
                for (int i = 0; i < 4; ++i) {
                    int e = i * 16 + lane;
                    if (w2 == 0) kss[e] = ksp[i]; else kss[e] += ksp[i];
                }
            }
        }
        __syncthreads();
    }
#pragma unroll
    for (int ii = 0; ii < 16; ++ii) {
        int idx = tid + ii * 256;
        Gp[(size_t)blockIdx.x * 4096 + idx] = gs[idx];
    }
    if (tid < 64) ksump[blockIdx.x * 64 + tid] = kss[tid];
}

// ---------------------------------------------------------------------------
// K2: reduce 16 partials -> Gb bf16 + ksum f32. grid 256 = 32 bh x 8 chunks.
// ---------------------------------------------------------------------------
__global__ __launch_bounds__(256) void gramr_kernel(
    const float* __restrict__ Gp, const float* __restrict__ ksump,
    unsigned short* __restrict__ Gb, float* __restrict__ ksum)
{
    int bh = blockIdx.x >> 3, c = blockIdx.x & 7;
    int t = threadIdx.x;
    int idx = c * 512 + t * 2;
    float s0 = 0.f, s1 = 0.f;
#pragma unroll
    for (int p = 0; p < 16; ++p) {
        const float* g = Gp + ((size_t)(bh * 16 + p)) * 4096 + idx;
        s0 += g[0]; s1 += g[1];
    }
    unsigned int pk = (unsigned int)f2bf(s0) | ((unsigned int)f2bf(s1) << 16);
    *(unsigned int*)&Gb[(size_t)bh * 4096 + idx] = pk;
    if (c == 0 && t < 64) {
        float s = 0.f;
#pragma unroll
        for (int p = 0; p < 16; ++p) s += ksump[(bh * 16 + p) * 64 + t];
        ksum[bh * 64 + t] = s;
    }
}

// ---------------------------------------------------------------------------
// K3: barrier-free single-pass attention. Block = 4 waves x 32 q-rows = 128
// rows of one (b,h); grid 512 XCD-swizzled. K and V B-frags read DIRECT from
// global (contiguous 16B, identical addresses across the block's 4 waves ->
// L1 reuse); P round-trips through wave-private LDS; NO __syncthreads in the
// K-loop -> compiler pipelines next-iter loads under exp/MFMA.
// Alpha (tau) computed in-block from G + ksum (quadratic-form trick).
// ---------------------------------------------------------------------------
__global__ __launch_bounds__(256, 2) void attn_kernel(
    const unsigned short* __restrict__ qt,
    const unsigned short* __restrict__ kt,
    const unsigned short* __restrict__ vt,
    const unsigned short* __restrict__ Gb,
    const float* __restrict__ ksum,
    float* __restrict__ out)
{
    __shared__ __align__(16) char lds[16384 + 1024];
    const int tid = threadIdx.x;
    const int lane = tid & 63;
    const int w = tid >> 6;
    const int m = lane & 15;
    const int quad = lane >> 4;
    char* ptb = lds + w * 4096;                          // wave-private P: 32x128B
    float2* ascr = (float2*)(lds + 16384) + w * 32;      // wave-private alpha scratch

    // XCD swizzle: blocks with blk%8==x handle bh in {4x..4x+3} -> each XCD's
    // L2 holds only 4 bh worth of K/V (2MB).
    int blk = blockIdx.x;
    int bh = (blk & 7) * 4 + ((blk >> 3) & 3);
    int l0 = (blk >> 5) * 128;
    int b = bh >> 3, h = bh & 7;

    const unsigned short* qtb = qt + (size_t)bh * L_ * E_;
    const unsigned short* ktb = kt + (size_t)bh * S_ * E_;
    const unsigned short* vtb = vt + (size_t)bh * E_ * S_;

    // Q B-fragments (register-resident): lane m <-> q-row l0+w*32+g*16+m
    short8 qf[2][2];
#pragma unroll
    for (int g = 0; g < 2; ++g)
#pragma unroll
        for (int c = 0; c < 2; ++c)
            qf[g][c] = *(const short8*)(qtb + (size_t)(l0 + w * 32 + g * 16 + m) * E_ + c * 32 + quad * 8);

    // ---- in-block alpha: T = Q*G, sumsq = sum T.Q, rowsum = Q.ksum ----
    float al[2], alm[2];
    {
        const unsigned short* gb = Gb + (size_t)bh * 4096;
        short8 gfr[4][2];
#pragma unroll
        for (int j = 0; j < 4; ++j)
#pragma unroll
            for (int c = 0; c < 2; ++c)
                gfr[j][c] = *(const short8*)(gb + (size_t)(j * 16 + m) * 64 + c * 32 + quad * 8);
        float ksl[4];
#pragma unroll
        for (int j = 0; j < 4; ++j) ksl[j] = ksum[bh * 64 + j * 16 + m];
#pragma unroll
        for (int g = 0; g < 2; ++g) {
            f32x4 accj[4];
#pragma unroll
            for (int j = 0; j < 4; ++j) {
                accj[j] = (f32x4){0.f, 0.f, 0.f, 0.f};
#pragma unroll
                for (int c = 0; c < 2; ++c)
                    accj[j] = __builtin_amdgcn_mfma_f32_16x16x32_bf16(qf[g][c], gfr[j][c], accj[j], 0, 0, 0);
            }
            float ps[4] = {0, 0, 0, 0}, pr[4] = {0, 0, 0, 0};
#pragma unroll
            for (int r = 0; r < 4; ++r)
#pragma unroll
                for (int j = 0; j < 4; ++j) {
                    float qv = bf2f(qtb[(size_t)(l0 + w * 32 + g * 16 + quad * 4 + r) * E_ + j * 16 + m]);
                    ps[r] = fmaf(accj[j][r], qv, ps[r]);
                    pr[r] = fmaf(qv, ksl[j], pr[r]);
                }
#pragma unroll
            for (int mask = 1; mask < 16; mask <<= 1)
#pragma unroll
                for (int r = 0; r < 4; ++r) {
                    ps[r] += __shfl_xor(ps[r], mask);
                    pr[r] += __shfl_xor(pr[r], mask);
                }
            if (m == 0) {
#pragma unroll
                for (int r = 0; r < 4; ++r) {
                    float sum = pr[r];
                    float mu = sum * (1.f / S_);
                    float var = (ps[r] - sum * mu) * (1.f / (S_ - 1));   // ddof=1
                    var = fmaxf(var, 0.f);
                    float tau = sqrtf(var + EPS);
                    float a = 0.125f / tau;                               // scale=1/8
                    ascr[g * 16 + quad * 4 + r] = make_float2(a, a * mu);
                }
            }
        }
        // wave-private LDS round-trip; compiler inserts the lgkm wait
#pragma unroll
        for (int g = 0; g < 2; ++g) {
            float2 a2 = ascr[g * 16 + m];
            al[g] = a2.x; alm[g] = a2.y;
        }
    }

    float dsum[2] = {0.f, 0.f};
    f32x4 oacc[2][4];
#pragma unroll
    for (int g = 0; g < 2; ++g)
#pragma unroll
        for (int et = 0; et < 4; ++et) oacc[g][et] = (f32x4){0.f, 0.f, 0.f, 0.f};

    // ---- barrier-free K-loop ----
    for (int st = 0; st < S_ / 64; ++st) {
        const unsigned short* kst = ktb + (size_t)st * 64 * E_;
        short8 kf[4][2];
#pragma unroll
        for (int nt = 0; nt < 4; ++nt) {
            kf[nt][0] = *(const short8*)(kst + (nt * 16 + m) * 64 + quad * 8);
            kf[nt][1] = *(const short8*)(kst + (nt * 16 + m) * 64 + 32 + quad * 8);
        }
        short8 vf[2][4];
#pragma unroll
        for (int c = 0; c < 2; ++c)
#pragma unroll
            for (int et = 0; et < 4; ++et)
                vf[c][et] = *(const short8*)(vtb + (size_t)(et * 16 + m) * S_ + st * 64 + c * 32 + quad * 8);

        // QK: scores transposed (lane m = q-row, s in (nt,quad,r))
#pragma unroll
        for (int nt = 0; nt < 4; ++nt) {
#pragma unroll
            for (int g = 0; g < 2; ++g) {
                f32x4 acc = {0.f, 0.f, 0.f, 0.f};
                acc = __builtin_amdgcn_mfma_f32_16x16x32_bf16(kf[nt][0], qf[g][0], acc, 0, 0, 0);
                acc = __builtin_amdgcn_mfma_f32_16x16x32_bf16(kf[nt][1], qf[g][1], acc, 0, 0, 0);
                unsigned int u0, u1, u2, u3;
                {
                    float p0 = __expf(fmaf(al[g], acc[0], -alm[g]));
                    float p1 = __expf(fmaf(al[g], acc[1], -alm[g]));
                    float p2 = __expf(fmaf(al[g], acc[2], -alm[g]));
                    float p3 = __expf(fmaf(al[g], acc[3], -alm[g]));
                    u0 = __float_as_uint(p0) & 0xffff0000u;
                    u1 = __float_as_uint(p1) & 0xffff0000u;
                    u2 = __float_as_uint(p2) & 0xffff0000u;
                    u3 = __float_as_uint(p3) & 0xffff0000u;
                    dsum[g] += __uint_as_float(u0) + __uint_as_float(u1)
                             + __uint_as_float(u2) + __uint_as_float(u3);
                }
                uint2 pk;
                pk.x = (u0 >> 16) | u1;
                pk.y = (u2 >> 16) | u3;
                *(uint2*)(ptb + swb(g * 16 + m, nt * 32 + quad * 8)) = pk;
            }
        }
        // PV (pt wave-private: lgkmcnt ordering suffices, no barrier)
#pragma unroll
        for (int g = 0; g < 2; ++g) {
            short8 pf0 = *(const short8*)(ptb + swb(g * 16 + m, quad * 16));
            short8 pf1 = *(const short8*)(ptb + swb(g * 16 + m, 64 + quad * 16));
#pragma unroll
            for (int et = 0; et < 4; ++et) {
                oacc[g][et] = __builtin_amdgcn_mfma_f32_16x16x32_bf16(pf0, vf[0][et], oacc[g][et], 0, 0, 0);
                oacc[g][et] = __builtin_amdgcn_mfma_f32_16x16x32_bf16(pf1, vf[1][et], oacc[g][et], 0, 0, 0);
            }
        }
    }

    // denominator reduce over quads, redistribute, store
#pragma unroll
    for (int g = 0; g < 2; ++g) {
        dsum[g] += __shfl_xor(dsum[g], 16);
        dsum[g] += __shfl_xor(dsum[g], 32);
    }
#pragma unroll
    for (int g = 0; g < 2; ++g) {
#pragma unroll
        for (int r = 0; r < 4; ++r) {
            float dn = __shfl(dsum[g], quad * 4 + r);
            float rd = 1.0f / dn;
            size_t row = (size_t)(b * L_ + l0 + w * 32 + g * 16 + quad * 4 + r);
#pragma unroll
            for (int et = 0; et < 4; ++et)
                out[(row * H_ + h) * E_ + et * 16 + m] = oacc[g][et][r] * rd;
        }
    }
}

extern "C" void kernel_launch(void* const* d_in, const int* in_sizes, int n_in,
                              void* d_out, int out_size, void* d_ws, size_t ws_size,
                              hipStream_t stream)
{
    const float* q = (const float*)d_in[0];
    const float* k = (const float*)d_in[1];
    const float* v = (const float*)d_in[2];
    // d_in[3] = attn_mask (unused)
    const float* dw = (const float*)d_in[4];
    const float* dp = (const float*)d_in[5];
    float* out = (float*)d_out;

    unsigned short* qt = (unsigned short*)d_ws;              // [B,H,L,E] bf16, 8MB
    unsigned short* kt = qt + (size_t)BH_ * L_ * E_;         // [B,H,S,E] bf16, 8MB
    unsigned short* vt = kt + (size_t)BH_ * S_ * E_;         // [B,H,E,S] bf16, 8MB
    unsigned short* Gb = vt + (size_t)BH_ * E_ * S_;         // [B,H,64,64] bf16
    float* fbase = (float*)(Gb + (size_t)BH_ * 4096);
    float* ksum  = fbase;                                    // [B,H,64]
    float* Gp    = fbase + BH_ * 64;                         // [512][4096] f32, 8MB
    float* ksump = Gp + (size_t)512 * 4096;                  // [512][64]

    pre_kernel<<<5120, 256, 0, stream>>>(q, k, v, qt, kt, vt, dw, dp);
    gramp_kernel<<<512, 256, 0, stream>>>(kt, Gp, ksump);
    gramr_kernel<<<256, 256, 0, stream>>>(Gp, ksump, Gb, ksum);
    attn_kernel<<<512, 256, 0, stream>>>(qt, kt, vt, Gb, ksum, out);
}

// Round 6
// 174.933 us; speedup vs baseline: 1.3109x; 1.3109x over previous
//
#include <hip/hip_runtime.h>
#include <math.h>

#define B_ 4
#define L_ 2048
#define S_ 2048
#define H_ 8
#define E_ 64
#define BH_ (B_*H_)
#define EPS 1e-6f

typedef __attribute__((ext_vector_type(8))) short short8;
typedef __attribute__((ext_vector_type(4))) float f32x4;

__device__ __forceinline__ unsigned short f2bf(float f) {
    unsigned int u = __float_as_uint(f);
    u = (u + 0x7fffu + ((u >> 16) & 1u)) >> 16;   // RNE
    return (unsigned short)u;
}

__device__ __forceinline__ float bf2f(unsigned short u) {
    return __uint_as_float(((unsigned int)u) << 16);
}

__device__ __forceinline__ float fast_tanh(float x) {
    float e = __expf(2.0f * x);
    return 1.0f - 2.0f / (e + 1.0f);
}

// XOR-swizzled LDS byte offset: rows of 128B, 16B chunks swizzled by row&7.
// Measured 0 bank conflicts for the K staging + frag-read pattern (round 2).
__device__ __forceinline__ int swb(int row, int byteoff) {
    return row * 128 + ((((byteoff >> 4) ^ (row & 7)) << 4) | (byteoff & 15));
}

// ---------------------------------------------------------------------------
// K0 (fused preprocessing, partitioned grid):
//  blocks [0,2048):    q transform  -> qt  [B,H,L,E] bf16
//  blocks [2048,4096): k transform  -> kt  [B,H,S,E] bf16
//  blocks [4096,5120): v transform  -> vt  MFMA-frag-tiled bf16:
//        vt[bh][st][ri*8+j], ri = et*128+c*64+quad*16+m,
//        value = V[b][st*64 + c*32+quad*8+j][h][et*16+m]
//        -> attn's vf[c][et] load is contiguous: lane reads ri=own, 16B.
// transform: std over H axis (8 vals, ddof=1); tanh(x*dw/(std+eps))*dp
// ---------------------------------------------------------------------------
__global__ __launch_bounds__(256) void pre_kernel(
    const float* __restrict__ xq, const float* __restrict__ xk,
    const float* __restrict__ xv,
    unsigned short* __restrict__ qt, unsigned short* __restrict__ kt,
    unsigned short* __restrict__ vt,
    const float* __restrict__ dwp, const float* __restrict__ dpp)
{
    __shared__ float ls[64][65];
    int bx = blockIdx.x;
    if (bx < 4096) {
        const float* x = (bx < 2048) ? xq : xk;
        unsigned short* xt = (bx < 2048) ? qt : kt;
        int g = (bx & 2047) * 256 + threadIdx.x;   // over B*L*E = 524288
        int e = g & 63;
        int bl = g >> 6;
        int b = bl >> 11;
        int l = bl & 2047;
        size_t base = (size_t)bl * (H_ * E_) + e;
        float v[8], s = 0.f, q = 0.f;
#pragma unroll
        for (int h = 0; h < 8; ++h) {
            float t = x[base + h * E_];
            v[h] = t; s += t; q += t * t;
        }
        float mean = s * 0.125f;
        float var = (q - s * mean) * (1.f / 7.f);   // ddof=1, N=8
        var = fmaxf(var, 0.f);
        float inv = 1.f / (sqrtf(var) + EPS);
        float wsc = dwp[0] * inv;
        float d = dpp[0];
#pragma unroll
        for (int h = 0; h < 8; ++h) {
            float t = fast_tanh(v[h] * wsc) * d;
            xt[((size_t)(b * H_ + h) * L_ + l) * E_ + e] = f2bf(t);
        }
    } else {
        int t2 = bx - 4096;
        int s0 = (t2 & 31) * 64;
        int h = (t2 >> 5) & 7, b = t2 >> 8;
        int t = threadIdx.x;
#pragma unroll
        for (int i = 0; i < 4; ++i) {
            int idx = t + i * 256;
            int r = idx >> 4, c4 = (idx & 15) * 4;
            const float4 f = *(const float4*)&xv[((size_t)(b * S_ + s0 + r) * H_ + h) * E_ + c4];
            ls[r][c4] = f.x; ls[r][c4 + 1] = f.y; ls[r][c4 + 2] = f.z; ls[r][c4 + 3] = f.w;
        }
        __syncthreads();
        size_t ob = ((size_t)(b * H_ + h) * (S_ / 64) + (s0 >> 6)) * 4096;
#pragma unroll
        for (int i = 0; i < 2; ++i) {
            int ri = t + i * 256;                  // 512 runs of 8 halfwords
            int et = ri >> 7, c = (ri >> 6) & 1, quad = (ri >> 4) & 3, m = ri & 15;
            int e = et * 16 + m, sb = c * 32 + quad * 8;
            unsigned short tmp[8];
#pragma unroll
            for (int j = 0; j < 8; ++j) tmp[j] = f2bf(ls[sb + j][e]);
            *(uint4*)&vt[ob + (size_t)ri * 8] = *(uint4*)tmp;
        }
    }
}

// ---------------------------------------------------------------------------
// K1: per (b,h): G = Kt^T Kt (64x64 f32 acc -> bf16) + ksum[e] = sum_s kt.
// 32 blocks, 256 thr. Reads kt in 16 chunks of 128 s (reg-prefetched),
// in-LDS transpose for the A==B fragments, 256 MFMA/wave, 4-wave reduce.
// ---------------------------------------------------------------------------
__global__ __launch_bounds__(256) void gram_kernel(
    const unsigned short* __restrict__ kt, unsigned short* __restrict__ Gb,
    float* __restrict__ ksum)
{
    __shared__ unsigned short ks[128 * 72];   // pad 72: transpose-friendly
    __shared__ float gs[4096];
    __shared__ float kss[64];
    int bh = blockIdx.x;
    const unsigned short* base = kt + (size_t)bh * S_ * E_;
    int tid = threadIdx.x, lane = tid & 63, w = tid >> 6;
    int m = lane & 15, quad = lane >> 4;

    f32x4 acc[4][4];
#pragma unroll
    for (int i = 0; i < 4; ++i)
#pragma unroll
        for (int j = 0; j < 4; ++j) acc[i][j] = (f32x4){0.f, 0.f, 0.f, 0.f};
    float ksp[4] = {0.f, 0.f, 0.f, 0.f};

    short8 stg[4];
#pragma unroll
    for (int i = 0; i < 4; ++i)
        stg[i] = *(const short8*)(base + (size_t)(tid + i * 256) * 8);

    for (int ch = 0; ch < 16; ++ch) {
        __syncthreads();                       // prior readers of ks done
#pragma unroll
        for (int i = 0; i < 4; ++i) {
            int u = tid + i * 256;
            *(short8*)&ks[(u >> 3) * 72 + (u & 7) * 8] = stg[i];
        }
        __syncthreads();
        if (ch < 15) {
#pragma unroll
            for (int i = 0; i < 4; ++i)
                stg[i] = *(const short8*)(base + (size_t)(ch + 1) * 8192 + (tid + i * 256) * 8);
        }
        int s0 = w * 32;
        short8 af[4];
#pragma unroll
        for (int i = 0; i < 4; ++i) {
            short8 a;
#pragma unroll
            for (int kk = 0; kk < 8; ++kk) {
                unsigned short uv = ks[(s0 + quad * 8 + kk) * 72 + i * 16 + m];
                a[kk] = (short)uv;
                ksp[i] += bf2f(uv);
            }
            af[i] = a;
        }
#pragma unroll
        for (int i = 0; i < 4; ++i)
#pragma unroll
            for (int j = 0; j < 4; ++j)
                acc[i][j] = __builtin_amdgcn_mfma_f32_16x16x32_bf16(af[i], af[j], acc[i][j], 0, 0, 0);
    }
#pragma unroll
    for (int i = 0; i < 4; ++i) {
        ksp[i] += __shfl_xor(ksp[i], 16);
        ksp[i] += __shfl_xor(ksp[i], 32);
    }
    for (int w2 = 0; w2 < 4; ++w2) {
        if (w == w2) {
#pragma unroll
            for (int i = 0; i < 4; ++i)
#pragma unroll
                for (int j = 0; j < 4; ++j)
#pragma unroll
                    for (int r = 0; r < 4; ++r) {
                        int idx = (i * 16 + quad * 4 + r) * 64 + j * 16 + m;
                        if (w2 == 0) gs[idx] = acc[i][j][r]; else gs[idx] += acc[i][j][r];
                    }
            if (lane < 16) {
#pragma unroll
                for (int i = 0; i < 4; ++i) {
                    int e = i * 16 + lane;
                    if (w2 == 0) kss[e] = ksp[i]; else kss[e] += ksp[i];
                }
            }
        }
        __syncthreads();
    }
#pragma unroll
    for (int ii = 0; ii < 16; ++ii) {
        int idx = tid + ii * 256;
        Gb[(size_t)bh * 4096 + idx] = f2bf(gs[idx]);
    }
    if (tid < 64) ksum[bh * 64 + tid] = kss[tid];
}

// ---------------------------------------------------------------------------
// K2: single-pass attention. Block = 4 waves x 32 q-rows = 128 rows of one
// (b,h); grid 512 XCD-swizzled. K staged in LDS (reg-prefetch dbuf, one
// barrier/iter — round-4 proven); V frags DIRECT from frag-tiled global
// (contiguous 1KB loads, VMEM pipe, no barrier dependency); P round-trips
// wave-private LDS. Alpha from Gram quadratic-form trick (in-block).
// ---------------------------------------------------------------------------
__global__ __launch_bounds__(256, 2) void attn_kernel(
    const unsigned short* __restrict__ qt,
    const unsigned short* __restrict__ kt,
    const unsigned short* __restrict__ vt,
    const unsigned short* __restrict__ Gb,
    const float* __restrict__ ksum,
    float* __restrict__ out)
{
    __shared__ __align__(16) char lds[33792];
    // [0,16384): K double buffer (2 x 8KB, swizzled 128B rows)
    // [16384,32768): wave-private P (4 x 4KB)
    // [32768,33792): alpha scratch
    const int tid = threadIdx.x;
    const int lane = tid & 63;
    const int w = tid >> 6;
    const int m = lane & 15;
    const int quad = lane >> 4;
    char* ptb = lds + 16384 + w * 4096;
    float2* ascr = (float2*)(lds + 32768) + w * 32;

    int blk = blockIdx.x;
    int bh = (blk & 7) * 4 + ((blk >> 3) & 3);   // XCD swizzle: 4 bh per XCD
    int l0 = (blk >> 5) * 128;
    int b = bh >> 3, h = bh & 7;

    const unsigned short* qtb = qt + (size_t)bh * L_ * E_;
    const unsigned short* ktb = kt + (size_t)bh * S_ * E_;
    const unsigned short* vtb = vt + (size_t)bh * (S_ / 64) * 4096;

    // Q B-fragments (register-resident): lane m <-> q-row l0+w*32+g*16+m
    short8 qf[2][2];
#pragma unroll
    for (int g = 0; g < 2; ++g)
#pragma unroll
        for (int c = 0; c < 2; ++c)
            qf[g][c] = *(const short8*)(qtb + (size_t)(l0 + w * 32 + g * 16 + m) * E_ + c * 32 + quad * 8);

    // ---- in-block alpha: T = Q*G, sumsq = sum T.Q, rowsum = Q.ksum ----
    float al[2], alm[2];
    {
        const unsigned short* gb = Gb + (size_t)bh * 4096;
        short8 gfr[4][2];
#pragma unroll
        for (int j = 0; j < 4; ++j)
#pragma unroll
            for (int c = 0; c < 2; ++c)
                gfr[j][c] = *(const short8*)(gb + (size_t)(j * 16 + m) * 64 + c * 32 + quad * 8);
        float ksl[4];
#pragma unroll
        for (int j = 0; j < 4; ++j) ksl[j] = ksum[bh * 64 + j * 16 + m];
#pragma unroll
        for (int g = 0; g < 2; ++g) {
            f32x4 accj[4];
#pragma unroll
            for (int j = 0; j < 4; ++j) {
                accj[j] = (f32x4){0.f, 0.f, 0.f, 0.f};
#pragma unroll
                for (int c = 0; c < 2; ++c)
                    accj[j] = __builtin_amdgcn_mfma_f32_16x16x32_bf16(qf[g][c], gfr[j][c], accj[j], 0, 0, 0);
            }
            float ps[4] = {0, 0, 0, 0}, pr[4] = {0, 0, 0, 0};
#pragma unroll
            for (int r = 0; r < 4; ++r)
#pragma unroll
                for (int j = 0; j < 4; ++j) {
                    float qv = bf2f(qtb[(size_t)(l0 + w * 32 + g * 16 + quad * 4 + r) * E_ + j * 16 + m]);
                    ps[r] = fmaf(accj[j][r], qv, ps[r]);
                    pr[r] = fmaf(qv, ksl[j], pr[r]);
                }
#pragma unroll
            for (int mask = 1; mask < 16; mask <<= 1)
#pragma unroll
                for (int r = 0; r < 4; ++r) {
                    ps[r] += __shfl_xor(ps[r], mask);
                    pr[r] += __shfl_xor(pr[r], mask);
                }
            if (m == 0) {
#pragma unroll
                for (int r = 0; r < 4; ++r) {
                    float sum = pr[r];
                    float mu = sum * (1.f / S_);
                    float var = (ps[r] - sum * mu) * (1.f / (S_ - 1));   // ddof=1
                    var = fmaxf(var, 0.f);
                    float tau = sqrtf(var + EPS);
                    float a = 0.125f / tau;                               // scale=1/8
                    ascr[g * 16 + quad * 4 + r] = make_float2(a, a * mu);
                }
            }
        }
#pragma unroll
        for (int g = 0; g < 2; ++g) {
            float2 a2 = ascr[g * 16 + m];
            al[g] = a2.x; alm[g] = a2.y;
        }
    }

    float dsum[2] = {0.f, 0.f};
    f32x4 oacc[2][4];
#pragma unroll
    for (int g = 0; g < 2; ++g)
#pragma unroll
        for (int et = 0; et < 4; ++et) oacc[g][et] = (f32x4){0.f, 0.f, 0.f, 0.f};

    // preload K tile 0 (8KB = 512 short8; 2 per thread)
    uint4 kr[2];
#pragma unroll
    for (int i = 0; i < 2; ++i)
        kr[i] = *(const uint4*)(ktb + (size_t)(tid + i * 256) * 8);
#pragma unroll
    for (int i = 0; i < 2; ++i) {
        int u = tid + i * 256;
        *(uint4*)(lds + swb(u >> 3, (u & 7) * 16)) = kr[i];
    }
    __syncthreads();

    for (int st = 0; st < S_ / 64; ++st) {
        char* kcur = lds + (st & 1) * 8192;
        char* knxt = lds + ((st + 1) & 1) * 8192;
        // prefetch next K tile into registers (covered by loop-end barrier)
        if (st < S_ / 64 - 1) {
#pragma unroll
            for (int i = 0; i < 2; ++i)
                kr[i] = *(const uint4*)(ktb + (size_t)(st + 1) * 4096 + (size_t)(tid + i * 256) * 8);
        }
        // V B-frags: contiguous 1KB wave-loads from frag-tiled vt
        const unsigned short* vstb = vtb + (size_t)st * 4096;
        short8 vf[2][4];
#pragma unroll
        for (int c = 0; c < 2; ++c)
#pragma unroll
            for (int et = 0; et < 4; ++et)
                vf[c][et] = *(const short8*)(vstb + et * 1024 + c * 512 + lane * 8);

        // QK: scores transposed (lane m = q-row, s in (nt,quad,r))
#pragma unroll
        for (int nt = 0; nt < 4; ++nt) {
            short8 kf0 = *(const short8*)(kcur + swb(nt * 16 + m, quad * 16));
            short8 kf1 = *(const short8*)(kcur + swb(nt * 16 + m, 64 + quad * 16));
#pragma unroll
            for (int g = 0; g < 2; ++g) {
                f32x4 acc = {0.f, 0.f, 0.f, 0.f};
                acc = __builtin_amdgcn_mfma_f32_16x16x32_bf16(kf0, qf[g][0], acc, 0, 0, 0);
                acc = __builtin_amdgcn_mfma_f32_16x16x32_bf16(kf1, qf[g][1], acc, 0, 0, 0);
                unsigned int u0, u1, u2, u3;
                {
                    float p0 = __expf(fmaf(al[g], acc[0], -alm[g]));
                    float p1 = __expf(fmaf(al[g], acc[1], -alm[g]));
                    float p2 = __expf(fmaf(al[g], acc[2], -alm[g]));
                    float p3 = __expf(fmaf(al[g], acc[3], -alm[g]));
                    u0 = __float_as_uint(p0) & 0xffff0000u;
                    u1 = __float_as_uint(p1) & 0xffff0000u;
                    u2 = __float_as_uint(p2) & 0xffff0000u;
                    u3 = __float_as_uint(p3) & 0xffff0000u;
                    dsum[g] += __uint_as_float(u0) + __uint_as_float(u1)
                             + __uint_as_float(u2) + __uint_as_float(u3);
                }
                uint2 pk;
                pk.x = (u0 >> 16) | u1;
                pk.y = (u2 >> 16) | u3;
                *(uint2*)(ptb + swb(g * 16 + m, nt * 32 + quad * 8)) = pk;
            }
        }
        // PV (pt wave-private: lgkmcnt ordering suffices, no barrier)
#pragma unroll
        for (int g = 0; g < 2; ++g) {
            short8 pf0 = *(const short8*)(ptb + swb(g * 16 + m, quad * 16));
            short8 pf1 = *(const short8*)(ptb + swb(g * 16 + m, 64 + quad * 16));
#pragma unroll
            for (int et = 0; et < 4; ++et) {
                oacc[g][et] = __builtin_amdgcn_mfma_f32_16x16x32_bf16(pf0, vf[0][et], oacc[g][et], 0, 0, 0);
                oacc[g][et] = __builtin_amdgcn_mfma_f32_16x16x32_bf16(pf1, vf[1][et], oacc[g][et], 0, 0, 0);
            }
        }
        // write prefetched K to the other buffer; single barrier per iter.
        // (all waves are in the same st between barriers -> read buf != write buf)
        if (st < S_ / 64 - 1) {
#pragma unroll
            for (int i = 0; i < 2; ++i) {
                int u = tid + i * 256;
                *(uint4*)(knxt + swb(u >> 3, (u & 7) * 16)) = kr[i];
            }
        }
        __syncthreads();
    }

    // denominator reduce over quads, redistribute, store
#pragma unroll
    for (int g = 0; g < 2; ++g) {
        dsum[g] += __shfl_xor(dsum[g], 16);
        dsum[g] += __shfl_xor(dsum[g], 32);
    }
#pragma unroll
    for (int g = 0; g < 2; ++g) {
#pragma unroll
        for (int r = 0; r < 4; ++r) {
            float dn = __shfl(dsum[g], quad * 4 + r);
            float rd = 1.0f / dn;
            size_t row = (size_t)(b * L_ + l0 + w * 32 + g * 16 + quad * 4 + r);
#pragma unroll
            for (int et = 0; et < 4; ++et)
                out[(row * H_ + h) * E_ + et * 16 + m] = oacc[g][et][r] * rd;
        }
    }
}

extern "C" void kernel_launch(void* const* d_in, const int* in_sizes, int n_in,
                              void* d_out, int out_size, void* d_ws, size_t ws_size,
                              hipStream_t stream)
{
    const float* q = (const float*)d_in[0];
    const float* k = (const float*)d_in[1];
    const float* v = (const float*)d_in[2];
    // d_in[3] = attn_mask (unused)
    const float* dw = (const float*)d_in[4];
    const float* dp = (const float*)d_in[5];
    float* out = (float*)d_out;

    unsigned short* qt = (unsigned short*)d_ws;              // [B,H,L,E] bf16, 8MB
    unsigned short* kt = qt + (size_t)BH_ * L_ * E_;         // [B,H,S,E] bf16, 8MB
    unsigned short* vt = kt + (size_t)BH_ * S_ * E_;         // frag-tiled, 8MB
    unsigned short* Gb = vt + (size_t)BH_ * E_ * S_;         // [B,H,64,64] bf16
    float* ksum = (float*)(Gb + (size_t)BH_ * 4096);         // [B,H,64]

    pre_kernel<<<5120, 256, 0, stream>>>(q, k, v, qt, kt, vt, dw, dp);
    gram_kernel<<<BH_, 256, 0, stream>>>(kt, Gb, ksum);
    attn_kernel<<<512, 256, 0, stream>>>(qt, kt, vt, Gb, ksum, out);
}